// Round 2
// baseline (771.119 us; speedup 1.0000x reference)
//
#include <hip/hip_runtime.h>

typedef short short8 __attribute__((ext_vector_type(8)));
typedef float f32x4 __attribute__((ext_vector_type(4)));
typedef float f32x2 __attribute__((ext_vector_type(2)));
typedef unsigned short u16x4 __attribute__((ext_vector_type(4)));

#define DEV static __device__ __forceinline__

DEV float b2f(unsigned short u) { return __uint_as_float(((unsigned)u) << 16); }
DEV unsigned short f2b(float f) {
    unsigned u = __float_as_uint(f);
    u += 0x7FFFu + ((u >> 16) & 1u);
    return (unsigned short)(u >> 16);
}
DEV float wred_sum(float v) {
#pragma unroll
    for (int o = 32; o; o >>= 1) v += __shfl_xor(v, o);
    return v;
}
DEV float wred_max(float v) {
#pragma unroll
    for (int o = 32; o; o >>= 1) v = fmaxf(v, __shfl_xor(v, o));
    return v;
}

// ---------------- LayerNorm: one block (256 thr) per row of 1024; f32 in ----------------
template <bool OUT_BF16>
__global__ __launch_bounds__(256) void ln_kernel(const float* __restrict__ in,
                                                 void* __restrict__ out_v,
                                                 const float* __restrict__ alpha_p,
                                                 const float* __restrict__ bias_p) {
    __shared__ float redA[4], redB[4];
    const int row = blockIdx.x;
    const int t = threadIdx.x;
    const int lane = t & 63, w = t >> 6;

    f32x4 xv = *(const f32x4*)&in[(size_t)row * 1024 + t * 4];

    float s = wred_sum(xv[0] + xv[1] + xv[2] + xv[3]);
    if (lane == 0) redA[w] = s;
    __syncthreads();
    float mean = (redA[0] + redA[1] + redA[2] + redA[3]) * (1.0f / 1024.0f);

    float d0 = xv[0] - mean, d1 = xv[1] - mean, d2 = xv[2] - mean, d3 = xv[3] - mean;
    float ss = wred_sum(d0 * d0 + d1 * d1 + d2 * d2 + d3 * d3);
    if (lane == 0) redB[w] = ss;
    __syncthreads();
    float var = (redB[0] + redB[1] + redB[2] + redB[3]) * (1.0f / 1023.0f);
    float denom = sqrtf(var) + 1e-9f;
    float alpha = alpha_p[0], bias = bias_p[0];
    float inv = alpha / denom;

    if (OUT_BF16) {
        u16x4 o;
        o[0] = f2b(d0 * inv + bias);
        o[1] = f2b(d1 * inv + bias);
        o[2] = f2b(d2 * inv + bias);
        o[3] = f2b(d3 * inv + bias);
        *(u16x4*)&((unsigned short*)out_v)[(size_t)row * 1024 + t * 4] = o;
    } else {
        f32x4 o;
        o[0] = d0 * inv + bias;
        o[1] = d1 * inv + bias;
        o[2] = d2 * inv + bias;
        o[3] = d3 * inv + bias;
        *(f32x4*)&((float*)out_v)[(size_t)row * 1024 + t * 4] = o;
    }
}

// ---------------- f32 -> bf16 transpose: in[R][C] f32 -> out[C][R] bf16 ----------------
__global__ __launch_bounds__(256) void transpose_cast_kernel(const float* __restrict__ in,
                                                             unsigned short* __restrict__ out,
                                                             int R, int C) {
    __shared__ unsigned short tile[32][33];
    const int c0 = blockIdx.x * 32, r0 = blockIdx.y * 32;
    const int x = threadIdx.x, y0 = threadIdx.y;
#pragma unroll
    for (int yy = y0; yy < 32; yy += 8) tile[yy][x] = f2b(in[(size_t)(r0 + yy) * C + c0 + x]);
    __syncthreads();
#pragma unroll
    for (int yy = y0; yy < 32; yy += 8) out[(size_t)(c0 + yy) * R + r0 + x] = tile[x][yy];
}

// ---------------- GEMM: C[M,N] = A[M,K](bf16) @ Bt[N,K]^T(bf16) + bias(f32) (+res f32) ----------------
// 128x128 tile, 4 waves 2x2, each wave 64x64 via 4x4 mfma_f32_16x16x32_bf16 frags.
template <bool RELU, bool RES, bool OUT_BF16>
__global__ __launch_bounds__(256) void gemm_bt(const unsigned short* __restrict__ A,
                                               const unsigned short* __restrict__ Bt,
                                               const float* __restrict__ bias,
                                               const float* __restrict__ res,
                                               void* __restrict__ C_v,
                                               int M, int N, int K) {
    __shared__ __align__(16) short As[128 * 40];
    __shared__ __align__(16) short Bs[128 * 40];

    const int t = threadIdx.x;
    const int lane = t & 63, w = t >> 6;
    const int wr = w >> 1, wc = w & 1;  // wave 2x2 -> 64x64 each
    const int m0 = blockIdx.y * 128, n0 = blockIdx.x * 128;
    const int lr = lane & 15, lk = (lane >> 4) * 8;

    f32x4 acc[4][4];
#pragma unroll
    for (int i = 0; i < 4; ++i)
#pragma unroll
        for (int j = 0; j < 4; ++j) acc[i][j] = (f32x4)0.0f;

    for (int k0 = 0; k0 < K; k0 += 32) {
        __syncthreads();
#pragma unroll
        for (int i = 0; i < 2; ++i) {
            int id = t + i * 256;       // 0..511
            int r = id >> 2;            // 0..127
            int c = id & 3;             // 0..3 (8 bf16 each)
            short8 av = *(const short8*)&A[(size_t)(m0 + r) * K + k0 + c * 8];
            *(short8*)&As[r * 40 + c * 8] = av;
            short8 bv = *(const short8*)&Bt[(size_t)(n0 + r) * K + k0 + c * 8];
            *(short8*)&Bs[r * 40 + c * 8] = bv;
        }
        __syncthreads();

        short8 af[4], bfr[4];
#pragma unroll
        for (int mi = 0; mi < 4; ++mi)
            af[mi] = *(const short8*)&As[(wr * 64 + mi * 16 + lr) * 40 + lk];
#pragma unroll
        for (int ni = 0; ni < 4; ++ni)
            bfr[ni] = *(const short8*)&Bs[(wc * 64 + ni * 16 + lr) * 40 + lk];
#pragma unroll
        for (int mi = 0; mi < 4; ++mi)
#pragma unroll
            for (int ni = 0; ni < 4; ++ni)
                acc[mi][ni] = __builtin_amdgcn_mfma_f32_16x16x32_bf16(af[mi], bfr[ni], acc[mi][ni], 0, 0, 0);
    }

    // epilogue: D row=(lane>>4)*4+i, col=lane&15
    const int lg = lane >> 4;
#pragma unroll
    for (int ni = 0; ni < 4; ++ni) {
        int col = n0 + wc * 64 + ni * 16 + lr;
        float bv = bias[col];
#pragma unroll
        for (int mi = 0; mi < 4; ++mi) {
            int row0 = m0 + wr * 64 + mi * 16 + lg * 4;
#pragma unroll
            for (int i = 0; i < 4; ++i) {
                int row = row0 + i;
                float x = acc[mi][ni][i] + bv;
                if (RES) x += res[(size_t)row * N + col];
                if (RELU) x = fmaxf(x, 0.0f);
                if (OUT_BF16)
                    ((unsigned short*)C_v)[(size_t)row * N + col] = f2b(x);
                else
                    ((float*)C_v)[(size_t)row * N + col] = x;
            }
        }
    }
}

// ---------------- Attention: q=k=v=p (source bug). One block = (b,h, 16 q rows) ----------------
// p layout [B,S,D] bf16 with head h at cols h*64..h*64+63.
__global__ __launch_bounds__(256) void attn_kernel(const unsigned short* __restrict__ p,
                                                   unsigned short* __restrict__ out) {
    __shared__ __align__(16) float Kt[64][66];      // k-tile, f32, padded
    __shared__ __align__(16) float q_lds[4][4][64]; // [wave][row][d]
    __shared__ __align__(16) float p_lds[4][64][4]; // [wave][key][row]

    const int t = threadIdx.x;
    const int lane = t & 63, w = t >> 6;
    const int qb = blockIdx.x;        // 0..63 (16 rows each)
    const int bh = blockIdx.y;        // 0..63
    const int b = bh >> 4, h = bh & 15;
    const unsigned short* P = p + (size_t)b * 1024 * 1024 + h * 64;

    // load q rows for this wave into LDS (f32)
#pragma unroll
    for (int r = 0; r < 4; ++r) {
        int s = qb * 16 + w * 4 + r;
        q_lds[w][r][lane] = b2f(P[(size_t)s * 1024 + lane]);
    }

    float o[4] = {0.f, 0.f, 0.f, 0.f};
    float mm[4] = {-1e30f, -1e30f, -1e30f, -1e30f};
    float ll[4] = {0.f, 0.f, 0.f, 0.f};

    for (int kt = 0; kt < 16; ++kt) {
        __syncthreads();
        // stage 64 keys x 64 dims as f32
#pragma unroll
        for (int pass = 0; pass < 2; ++pass) {
            int id = pass * 256 + t;
            int row = id >> 3, c = id & 7;
            short8 v = *(const short8*)&P[(size_t)(kt * 64 + row) * 1024 + c * 8];
#pragma unroll
            for (int i = 0; i < 8; ++i) Kt[row][c * 8 + i] = b2f((unsigned short)v[i]);
        }
        __syncthreads();

        // scores: lane j owns key j
        float s0 = 0.f, s1 = 0.f, s2 = 0.f, s3 = 0.f;
#pragma unroll
        for (int d = 0; d < 64; d += 2) {
            f32x2 kv = *(const f32x2*)&Kt[lane][d];
            f32x2 q0 = *(const f32x2*)&q_lds[w][0][d];
            f32x2 q1 = *(const f32x2*)&q_lds[w][1][d];
            f32x2 q2 = *(const f32x2*)&q_lds[w][2][d];
            f32x2 q3 = *(const f32x2*)&q_lds[w][3][d];
            s0 += kv[0] * q0[0] + kv[1] * q0[1];
            s1 += kv[0] * q1[0] + kv[1] * q1[1];
            s2 += kv[0] * q2[0] + kv[1] * q2[1];
            s3 += kv[0] * q3[0] + kv[1] * q3[1];
        }
        float sc[4] = {s0 * 0.125f, s1 * 0.125f, s2 * 0.125f, s3 * 0.125f};

#pragma unroll
        for (int r = 0; r < 4; ++r) {
            float tmax = wred_max(sc[r]);
            float m_new = fmaxf(mm[r], tmax);
            float scale = __expf(mm[r] - m_new);
            float pj = __expf(sc[r] - m_new);
            float psum = wred_sum(pj);
            ll[r] = ll[r] * scale + psum;
            o[r] *= scale;
            mm[r] = m_new;
            p_lds[w][lane][r] = pj;
        }

        // PV: lane d owns output dim d
#pragma unroll
        for (int j = 0; j < 64; ++j) {
            f32x4 pv = *(const f32x4*)&p_lds[w][j][0];
            float v = Kt[j][lane];
            o[0] += pv[0] * v;
            o[1] += pv[1] * v;
            o[2] += pv[2] * v;
            o[3] += pv[3] * v;
        }
    }

    unsigned short* O = out + (size_t)b * 1024 * 1024 + h * 64;
#pragma unroll
    for (int r = 0; r < 4; ++r) {
        int s = qb * 16 + w * 4 + r;
        O[(size_t)s * 1024 + lane] = f2b(o[r] / ll[r]);
    }
}

// ---------------- launch ----------------
extern "C" void kernel_launch(void* const* d_in, const int* in_sizes, int n_in,
                              void* d_out, int out_size, void* d_ws, size_t ws_size,
                              hipStream_t stream) {
    const float* x = (const float*)d_in[0];
    const float* wq_w = (const float*)d_in[1];
    const float* wq_b = (const float*)d_in[2];
    const float* wo_w = (const float*)d_in[3];
    const float* wo_b = (const float*)d_in[4];
    const float* ff1_w = (const float*)d_in[5];
    const float* ff1_b = (const float*)d_in[6];
    const float* ff2_w = (const float*)d_in[7];
    const float* ff2_b = (const float*)d_in[8];
    const float* alpha1 = (const float*)d_in[9];
    const float* bias1 = (const float*)d_in[10];
    const float* alpha2 = (const float*)d_in[11];
    const float* bias2 = (const float*)d_in[12];
    const float* alpha3 = (const float*)d_in[13];
    const float* bias3 = (const float*)d_in[14];
    float* out = (float*)d_out;

    const size_t MB = 1u << 20;
    char* ws = (char*)d_ws;
    unsigned short* wq_t = (unsigned short*)(ws + 0 * MB);    // [1024,1024] bf16
    unsigned short* wo_t = (unsigned short*)(ws + 2 * MB);    // [1024,1024] bf16
    unsigned short* ff1_t = (unsigned short*)(ws + 4 * MB);   // [4096,1024] bf16
    unsigned short* ff2_t = (unsigned short*)(ws + 12 * MB);  // [1024,4096] bf16
    unsigned short* lnbuf = (unsigned short*)(ws + 20 * MB);  // [4096,1024] bf16 (ln1, then ln2)
    unsigned short* pbuf = (unsigned short*)(ws + 28 * MB);   // [4096,1024] bf16
    unsigned short* attn = (unsigned short*)(ws + 36 * MB);   // [4096,1024] bf16
    float* h1 = (float*)(ws + 44 * MB);                       // [4096,1024] f32
    unsigned short* mid = (unsigned short*)(ws + 60 * MB);    // [4096,4096] bf16
    float* h2 = (float*)(ws + 28 * MB);                       // [4096,1024] f32 (reuses pbuf+attn)

    const int M = 4096;  // B*S

    // transpose+cast weights -> bf16 [N,K]
    transpose_cast_kernel<<<dim3(1024 / 32, 1024 / 32), dim3(32, 8), 0, stream>>>(wq_w, wq_t, 1024, 1024);
    transpose_cast_kernel<<<dim3(1024 / 32, 1024 / 32), dim3(32, 8), 0, stream>>>(wo_w, wo_t, 1024, 1024);
    transpose_cast_kernel<<<dim3(4096 / 32, 1024 / 32), dim3(32, 8), 0, stream>>>(ff1_w, ff1_t, 1024, 4096);
    transpose_cast_kernel<<<dim3(1024 / 32, 4096 / 32), dim3(32, 8), 0, stream>>>(ff2_w, ff2_t, 4096, 1024);

    // ln1 = LN(x) -> bf16
    ln_kernel<true><<<M, 256, 0, stream>>>(x, lnbuf, alpha1, bias1);
    // p = ln1 @ wq + wq_b -> bf16
    gemm_bt<false, false, true><<<dim3(1024 / 128, M / 128), 256, 0, stream>>>(lnbuf, wq_t, wq_b, nullptr, pbuf, M, 1024, 1024);
    // attention (q=k=v=p) -> bf16
    attn_kernel<<<dim3(64, 64), 256, 0, stream>>>(pbuf, attn);
    // h1 = x + attn @ wo + wo_b -> f32
    gemm_bt<false, true, false><<<dim3(1024 / 128, M / 128), 256, 0, stream>>>(attn, wo_t, wo_b, x, h1, M, 1024, 1024);
    // ln2 = LN(h1) -> bf16
    ln_kernel<true><<<M, 256, 0, stream>>>(h1, lnbuf, alpha2, bias2);
    // mid = relu(ln2 @ ff1 + ff1_b) -> bf16
    gemm_bt<true, false, true><<<dim3(4096 / 128, M / 128), 256, 0, stream>>>(lnbuf, ff1_t, ff1_b, nullptr, mid, M, 4096, 1024);
    // h2 = h1 + mid @ ff2 + ff2_b -> f32
    gemm_bt<false, true, false><<<dim3(1024 / 128, M / 128), 256, 0, stream>>>(mid, ff2_t, ff2_b, h1, h2, M, 1024, 4096);
    // out = LN(h2) -> f32
    ln_kernel<false><<<M, 256, 0, stream>>>(h2, out, alpha3, bias3);
}

// Round 3
// 308.746 us; speedup vs baseline: 2.4976x; 2.4976x over previous
//
#include <hip/hip_runtime.h>

typedef short short8 __attribute__((ext_vector_type(8)));
typedef float f32x4 __attribute__((ext_vector_type(4)));
typedef unsigned short u16x4 __attribute__((ext_vector_type(4)));

#define DEV static __device__ __forceinline__

DEV float b2f(unsigned short u) { return __uint_as_float(((unsigned)u) << 16); }
DEV unsigned short f2b(float f) {
    unsigned u = __float_as_uint(f);
    u += 0x7FFFu + ((u >> 16) & 1u);
    return (unsigned short)(u >> 16);
}
DEV float wred_sum(float v) {
#pragma unroll
    for (int o = 32; o; o >>= 1) v += __shfl_xor(v, o);
    return v;
}

// ---------------- LayerNorm: one block (256 thr) per row of 1024; f32 in ----------------
template <bool OUT_BF16>
__global__ __launch_bounds__(256) void ln_kernel(const float* __restrict__ in,
                                                 void* __restrict__ out_v,
                                                 const float* __restrict__ alpha_p,
                                                 const float* __restrict__ bias_p) {
    __shared__ float redA[4], redB[4];
    const int row = blockIdx.x;
    const int t = threadIdx.x;
    const int lane = t & 63, w = t >> 6;

    f32x4 xv = *(const f32x4*)&in[(size_t)row * 1024 + t * 4];

    float s = wred_sum(xv[0] + xv[1] + xv[2] + xv[3]);
    if (lane == 0) redA[w] = s;
    __syncthreads();
    float mean = (redA[0] + redA[1] + redA[2] + redA[3]) * (1.0f / 1024.0f);

    float d0 = xv[0] - mean, d1 = xv[1] - mean, d2 = xv[2] - mean, d3 = xv[3] - mean;
    float ss = wred_sum(d0 * d0 + d1 * d1 + d2 * d2 + d3 * d3);
    if (lane == 0) redB[w] = ss;
    __syncthreads();
    float var = (redB[0] + redB[1] + redB[2] + redB[3]) * (1.0f / 1023.0f);
    float denom = sqrtf(var) + 1e-9f;
    float inv = alpha_p[0] / denom;
    float bias = bias_p[0];

    if (OUT_BF16) {
        u16x4 o;
        o[0] = f2b(d0 * inv + bias);
        o[1] = f2b(d1 * inv + bias);
        o[2] = f2b(d2 * inv + bias);
        o[3] = f2b(d3 * inv + bias);
        *(u16x4*)&((unsigned short*)out_v)[(size_t)row * 1024 + t * 4] = o;
    } else {
        f32x4 o;
        o[0] = d0 * inv + bias;
        o[1] = d1 * inv + bias;
        o[2] = d2 * inv + bias;
        o[3] = d3 * inv + bias;
        *(f32x4*)&((float*)out_v)[(size_t)row * 1024 + t * 4] = o;
    }
}

// ---------------- f32 -> bf16 transpose: in[R][C] f32 -> out[C][R] bf16 ----------------
__global__ __launch_bounds__(256) void transpose_cast_kernel(const float* __restrict__ in,
                                                             unsigned short* __restrict__ out,
                                                             int R, int C) {
    __shared__ unsigned short tile[32][33];
    const int c0 = blockIdx.x * 32, r0 = blockIdx.y * 32;
    const int x = threadIdx.x, y0 = threadIdx.y;
#pragma unroll
    for (int yy = y0; yy < 32; yy += 8) tile[yy][x] = f2b(in[(size_t)(r0 + yy) * C + c0 + x]);
    __syncthreads();
#pragma unroll
    for (int yy = y0; yy < 32; yy += 8) out[(size_t)(c0 + yy) * R + r0 + x] = tile[x][yy];
}

// ---------------- bf16 [b][s][d] -> [b][d][s] transpose (for V^T staging) ----------------
__global__ __launch_bounds__(256) void transpose_bf16_batch(const unsigned short* __restrict__ in,
                                                            unsigned short* __restrict__ out) {
    __shared__ unsigned short tile[32][33];
    const int b = blockIdx.z;
    const int d0 = blockIdx.x * 32, s0 = blockIdx.y * 32;
    const unsigned short* I = in + (size_t)b * 1024 * 1024;
    unsigned short* O = out + (size_t)b * 1024 * 1024;
    const int x = threadIdx.x, y0 = threadIdx.y;
#pragma unroll
    for (int yy = y0; yy < 32; yy += 8) tile[yy][x] = I[(size_t)(s0 + yy) * 1024 + d0 + x];
    __syncthreads();
#pragma unroll
    for (int yy = y0; yy < 32; yy += 8) O[(size_t)(d0 + yy) * 1024 + s0 + x] = tile[x][yy];
}

// ---------------- GEMM: C[M,N] = A[M,K](bf16) @ Bt[N,K]^T(bf16) + bias(f32) (+res f32) ----------------
template <bool RELU, bool RES, bool OUT_BF16>
__global__ __launch_bounds__(256) void gemm_bt(const unsigned short* __restrict__ A,
                                               const unsigned short* __restrict__ Bt,
                                               const float* __restrict__ bias,
                                               const float* __restrict__ res,
                                               void* __restrict__ C_v,
                                               int M, int N, int K) {
    __shared__ __align__(16) short As[128 * 40];
    __shared__ __align__(16) short Bs[128 * 40];

    const int t = threadIdx.x;
    const int lane = t & 63, w = t >> 6;
    const int wr = w >> 1, wc = w & 1;
    const int m0 = blockIdx.y * 128, n0 = blockIdx.x * 128;
    const int lr = lane & 15, lk = (lane >> 4) * 8;

    f32x4 acc[4][4];
#pragma unroll
    for (int i = 0; i < 4; ++i)
#pragma unroll
        for (int j = 0; j < 4; ++j) acc[i][j] = (f32x4)0.0f;

    for (int k0 = 0; k0 < K; k0 += 32) {
        __syncthreads();
#pragma unroll
        for (int i = 0; i < 2; ++i) {
            int id = t + i * 256;
            int r = id >> 2;
            int c = id & 3;
            short8 av = *(const short8*)&A[(size_t)(m0 + r) * K + k0 + c * 8];
            *(short8*)&As[r * 40 + c * 8] = av;
            short8 bv = *(const short8*)&Bt[(size_t)(n0 + r) * K + k0 + c * 8];
            *(short8*)&Bs[r * 40 + c * 8] = bv;
        }
        __syncthreads();

        short8 af[4], bfr[4];
#pragma unroll
        for (int mi = 0; mi < 4; ++mi)
            af[mi] = *(const short8*)&As[(wr * 64 + mi * 16 + lr) * 40 + lk];
#pragma unroll
        for (int ni = 0; ni < 4; ++ni)
            bfr[ni] = *(const short8*)&Bs[(wc * 64 + ni * 16 + lr) * 40 + lk];
#pragma unroll
        for (int mi = 0; mi < 4; ++mi)
#pragma unroll
            for (int ni = 0; ni < 4; ++ni)
                acc[mi][ni] = __builtin_amdgcn_mfma_f32_16x16x32_bf16(af[mi], bfr[ni], acc[mi][ni], 0, 0, 0);
    }

    const int lg = lane >> 4;
#pragma unroll
    for (int ni = 0; ni < 4; ++ni) {
        int col = n0 + wc * 64 + ni * 16 + lr;
        float bv = bias[col];
#pragma unroll
        for (int mi = 0; mi < 4; ++mi) {
            int row0 = m0 + wr * 64 + mi * 16 + lg * 4;
#pragma unroll
            for (int i = 0; i < 4; ++i) {
                int row = row0 + i;
                float x = acc[mi][ni][i] + bv;
                if (RES) x += res[(size_t)row * N + col];
                if (RELU) x = fmaxf(x, 0.0f);
                if (OUT_BF16)
                    ((unsigned short*)C_v)[(size_t)row * N + col] = f2b(x);
                else
                    ((float*)C_v)[(size_t)row * N + col] = x;
            }
        }
    }
}

// ---------------- MFMA flash attention: q=k=v=p (source bug) ----------------
// p: [B,S,D] bf16, pT: [B,D,S] bf16 (per-batch transpose). Block = (qblk 64 rows, b*h).
// 4 waves; wave owns 16 q-rows. KV tiles of 64 keys. All LDS tiles XOR-swizzled:
// element index d ^= (row&7)<<3  (i.e. byte ^= (row&7)<<4) on BOTH write and read.
__global__ __launch_bounds__(256) void attn_mfma_kernel(const unsigned short* __restrict__ p,
                                                        const unsigned short* __restrict__ pT,
                                                        unsigned short* __restrict__ out) {
    __shared__ __align__(16) unsigned short Ks[64 * 64];   // [key][d]
    __shared__ __align__(16) unsigned short Vt[64 * 64];   // [d][key]
    __shared__ __align__(16) unsigned short Ps[4 * 16 * 64];  // per-wave [q][key]

    const int t = threadIdx.x;
    const int lane = t & 63, w = t >> 6;
    const int lr = lane & 15, g = lane >> 4;
    const int qblk = blockIdx.x;   // 0..15
    const int bh = blockIdx.y;     // 0..63
    const int b = bh >> 4, h = bh & 15;

    const unsigned short* Pm = p + (size_t)b * (1024 * 1024) + h * 64;                   // rows: s
    const unsigned short* PT = pT + (size_t)b * (1024 * 1024) + (size_t)(h * 64) * 1024; // rows: d

    const int q0 = qblk * 64 + w * 16;
    // Q A-frags in registers: lane holds row q0+lr, k(d) = g*8..g*8+7 (+32)
    short8 qa0 = *(const short8*)&Pm[(size_t)(q0 + lr) * 1024 + g * 8];
    short8 qa1 = *(const short8*)&Pm[(size_t)(q0 + lr) * 1024 + 32 + g * 8];

    f32x4 acc[4];  // O accum: dg -> 4 rows (C-layout: col=d=lr+16dg, row=q=g*4+reg)
#pragma unroll
    for (int i = 0; i < 4; ++i) acc[i] = (f32x4)0.0f;
    float mrow[4] = {-1e30f, -1e30f, -1e30f, -1e30f};
    float lsum[4] = {0.f, 0.f, 0.f, 0.f};

    unsigned short* Pw = &Ps[w * 16 * 64];

    for (int kt = 0; kt < 16; ++kt) {
        const int key0 = kt * 64;
        __syncthreads();
        // stage K [key][d] and V^T [d][key], 64x64 bf16 each, swizzled writes
#pragma unroll
        for (int i = 0; i < 2; ++i) {
            int id = t + i * 256;
            int row = id >> 3, ch = (id & 7) * 8;
            int sw = ch ^ ((row & 7) << 3);
            short8 kv = *(const short8*)&Pm[(size_t)(key0 + row) * 1024 + ch];
            *(short8*)&Ks[row * 64 + sw] = kv;
            short8 vv = *(const short8*)&PT[(size_t)row * 1024 + key0 + ch];
            *(short8*)&Vt[row * 64 + sw] = vv;
        }
        __syncthreads();

        // QK^T: S[q][key], key-groups of 16
        f32x4 s_acc[4];
#pragma unroll
        for (int kg = 0; kg < 4; ++kg) {
            s_acc[kg] = (f32x4)0.0f;
            int krow = kg * 16 + lr;
            int swz = (krow & 7) << 3;
            short8 kb0 = *(const short8*)&Ks[krow * 64 + ((g * 8) ^ swz)];
            short8 kb1 = *(const short8*)&Ks[krow * 64 + ((32 + g * 8) ^ swz)];
            s_acc[kg] = __builtin_amdgcn_mfma_f32_16x16x32_bf16(qa0, kb0, s_acc[kg], 0, 0, 0);
            s_acc[kg] = __builtin_amdgcn_mfma_f32_16x16x32_bf16(qa1, kb1, s_acc[kg], 0, 0, 0);
        }

        // online softmax: row q=g*4+reg lives across 16 lanes (same g), 4 kg each
#pragma unroll
        for (int reg = 0; reg < 4; ++reg) {
            float mx = fmaxf(fmaxf(s_acc[0][reg], s_acc[1][reg]),
                             fmaxf(s_acc[2][reg], s_acc[3][reg])) * 0.125f;
            mx = fmaxf(mx, __shfl_xor(mx, 1));
            mx = fmaxf(mx, __shfl_xor(mx, 2));
            mx = fmaxf(mx, __shfl_xor(mx, 4));
            mx = fmaxf(mx, __shfl_xor(mx, 8));
            float mnew = fmaxf(mrow[reg], mx);
            float scale = __expf(mrow[reg] - mnew);
            mrow[reg] = mnew;
            float psum = 0.f;
#pragma unroll
            for (int kg = 0; kg < 4; ++kg) {
                float pv = __expf(s_acc[kg][reg] * 0.125f - mnew);
                s_acc[kg][reg] = pv;
                psum += pv;
            }
            psum += __shfl_xor(psum, 1);
            psum += __shfl_xor(psum, 2);
            psum += __shfl_xor(psum, 4);
            psum += __shfl_xor(psum, 8);
            lsum[reg] = lsum[reg] * scale + psum;
#pragma unroll
            for (int dg = 0; dg < 4; ++dg) acc[dg][reg] *= scale;
        }

        // P (C-layout) -> LDS -> A-frag layout. Per-wave buffer, no barrier needed.
#pragma unroll
        for (int reg = 0; reg < 4; ++reg) {
            int q = g * 4 + reg;
            int swz = (q & 7) << 3;
#pragma unroll
            for (int kg = 0; kg < 4; ++kg) {
                int key = lr + 16 * kg;
                Pw[q * 64 + (key ^ swz)] = f2b(s_acc[kg][reg]);
            }
        }
        int pswz = (lr & 7) << 3;
        short8 pa0 = *(const short8*)&Pw[lr * 64 + ((g * 8) ^ pswz)];
        short8 pa1 = *(const short8*)&Pw[lr * 64 + ((32 + g * 8) ^ pswz)];

        // PV: O[q][d] += P[q][key] * V[key][d]; B-frag from Vt rows d
#pragma unroll
        for (int dg = 0; dg < 4; ++dg) {
            int drow = dg * 16 + lr;
            int swz = (drow & 7) << 3;
            short8 vb0 = *(const short8*)&Vt[drow * 64 + ((g * 8) ^ swz)];
            short8 vb1 = *(const short8*)&Vt[drow * 64 + ((32 + g * 8) ^ swz)];
            acc[dg] = __builtin_amdgcn_mfma_f32_16x16x32_bf16(pa0, vb0, acc[dg], 0, 0, 0);
            acc[dg] = __builtin_amdgcn_mfma_f32_16x16x32_bf16(pa1, vb1, acc[dg], 0, 0, 0);
        }
    }

    // epilogue
    unsigned short* O = out + (size_t)b * (1024 * 1024) + h * 64;
#pragma unroll
    for (int reg = 0; reg < 4; ++reg) {
        float inv = 1.0f / lsum[reg];
        int q = q0 + g * 4 + reg;
#pragma unroll
        for (int dg = 0; dg < 4; ++dg) {
            O[(size_t)q * 1024 + dg * 16 + lr] = f2b(acc[dg][reg] * inv);
        }
    }
}

// ---------------- launch ----------------
extern "C" void kernel_launch(void* const* d_in, const int* in_sizes, int n_in,
                              void* d_out, int out_size, void* d_ws, size_t ws_size,
                              hipStream_t stream) {
    const float* x = (const float*)d_in[0];
    const float* wq_w = (const float*)d_in[1];
    const float* wq_b = (const float*)d_in[2];
    const float* wo_w = (const float*)d_in[3];
    const float* wo_b = (const float*)d_in[4];
    const float* ff1_w = (const float*)d_in[5];
    const float* ff1_b = (const float*)d_in[6];
    const float* ff2_w = (const float*)d_in[7];
    const float* ff2_b = (const float*)d_in[8];
    const float* alpha1 = (const float*)d_in[9];
    const float* bias1 = (const float*)d_in[10];
    const float* alpha2 = (const float*)d_in[11];
    const float* bias2 = (const float*)d_in[12];
    const float* alpha3 = (const float*)d_in[13];
    const float* bias3 = (const float*)d_in[14];
    float* out = (float*)d_out;

    const size_t MB = 1u << 20;
    char* ws = (char*)d_ws;
    unsigned short* wq_t = (unsigned short*)(ws + 0 * MB);    // [1024,1024] bf16
    unsigned short* wo_t = (unsigned short*)(ws + 2 * MB);    // [1024,1024] bf16
    unsigned short* ff1_t = (unsigned short*)(ws + 4 * MB);   // [4096,1024] bf16
    unsigned short* ff2_t = (unsigned short*)(ws + 12 * MB);  // [1024,4096] bf16
    unsigned short* lnbuf = (unsigned short*)(ws + 20 * MB);  // [4096,1024] bf16
    unsigned short* pbuf = (unsigned short*)(ws + 28 * MB);   // [4096,1024] bf16
    unsigned short* attn = (unsigned short*)(ws + 36 * MB);   // [4096,1024] bf16
    float* h1 = (float*)(ws + 44 * MB);                       // [4096,1024] f32
    unsigned short* pbT = (unsigned short*)(ws + 60 * MB);    // [4,1024,1024] bf16 (aliases mid; dead before ffn1)
    unsigned short* mid = (unsigned short*)(ws + 60 * MB);    // [4096,4096] bf16
    float* h2 = (float*)(ws + 28 * MB);                       // f32 (reuses pbuf+attn region)

    const int M = 4096;  // B*S

    transpose_cast_kernel<<<dim3(32, 32), dim3(32, 8), 0, stream>>>(wq_w, wq_t, 1024, 1024);
    transpose_cast_kernel<<<dim3(32, 32), dim3(32, 8), 0, stream>>>(wo_w, wo_t, 1024, 1024);
    transpose_cast_kernel<<<dim3(128, 32), dim3(32, 8), 0, stream>>>(ff1_w, ff1_t, 1024, 4096);
    transpose_cast_kernel<<<dim3(32, 128), dim3(32, 8), 0, stream>>>(ff2_w, ff2_t, 4096, 1024);

    // ln1 = LN(x) -> bf16
    ln_kernel<true><<<M, 256, 0, stream>>>(x, lnbuf, alpha1, bias1);
    // p = ln1 @ wq + wq_b -> bf16
    gemm_bt<false, false, true><<<dim3(8, 32), 256, 0, stream>>>(lnbuf, wq_t, wq_b, nullptr, pbuf, M, 1024, 1024);
    // pT = per-batch transpose of p (for V^T staging)
    transpose_bf16_batch<<<dim3(32, 32, 4), dim3(32, 8), 0, stream>>>(pbuf, pbT);
    // attention (q=k=v=p) -> bf16
    attn_mfma_kernel<<<dim3(16, 64), 256, 0, stream>>>(pbuf, pbT, attn);
    // h1 = x + attn @ wo + wo_b -> f32
    gemm_bt<false, true, false><<<dim3(8, 32), 256, 0, stream>>>(attn, wo_t, wo_b, x, h1, M, 1024, 1024);
    // ln2 = LN(h1) -> bf16
    ln_kernel<true><<<M, 256, 0, stream>>>(h1, lnbuf, alpha2, bias2);
    // mid = relu(ln2 @ ff1 + ff1_b) -> bf16
    gemm_bt<true, false, true><<<dim3(32, 32), 256, 0, stream>>>(lnbuf, ff1_t, ff1_b, nullptr, mid, M, 4096, 1024);
    // h2 = h1 + mid @ ff2 + ff2_b -> f32
    gemm_bt<false, true, false><<<dim3(8, 32), 256, 0, stream>>>(mid, ff2_t, ff2_b, h1, h2, M, 1024, 4096);
    // out = LN(h2) -> f32
    ln_kernel<false><<<M, 256, 0, stream>>>(h2, out, alpha3, bias3);
}

// Round 4
// 258.764 us; speedup vs baseline: 2.9800x; 1.1932x over previous
//
#include <hip/hip_runtime.h>

typedef short short8 __attribute__((ext_vector_type(8)));
typedef float f32x4 __attribute__((ext_vector_type(4)));
typedef unsigned short u16x4 __attribute__((ext_vector_type(4)));

#define DEV static __device__ __forceinline__

DEV float b2f(unsigned short u) { return __uint_as_float(((unsigned)u) << 16); }
DEV unsigned short f2b(float f) {
    unsigned u = __float_as_uint(f);
    u += 0x7FFFu + ((u >> 16) & 1u);
    return (unsigned short)(u >> 16);
}
DEV float wred_sum(float v) {
#pragma unroll
    for (int o = 32; o; o >>= 1) v += __shfl_xor(v, o);
    return v;
}

DEV void gld_lds16(const unsigned short* g, unsigned short* l) {
    __builtin_amdgcn_global_load_lds((const __attribute__((address_space(1))) void*)g,
                                     (__attribute__((address_space(3))) void*)l, 16, 0, 0);
}

// ---------------- LayerNorm ----------------
template <bool OUT_BF16>
__global__ __launch_bounds__(256) void ln_kernel(const float* __restrict__ in,
                                                 void* __restrict__ out_v,
                                                 const float* __restrict__ alpha_p,
                                                 const float* __restrict__ bias_p) {
    __shared__ float redA[4], redB[4];
    const int row = blockIdx.x;
    const int t = threadIdx.x;
    const int lane = t & 63, w = t >> 6;

    f32x4 xv = *(const f32x4*)&in[(size_t)row * 1024 + t * 4];

    float s = wred_sum(xv[0] + xv[1] + xv[2] + xv[3]);
    if (lane == 0) redA[w] = s;
    __syncthreads();
    float mean = (redA[0] + redA[1] + redA[2] + redA[3]) * (1.0f / 1024.0f);

    float d0 = xv[0] - mean, d1 = xv[1] - mean, d2 = xv[2] - mean, d3 = xv[3] - mean;
    float ss = wred_sum(d0 * d0 + d1 * d1 + d2 * d2 + d3 * d3);
    if (lane == 0) redB[w] = ss;
    __syncthreads();
    float var = (redB[0] + redB[1] + redB[2] + redB[3]) * (1.0f / 1023.0f);
    float denom = sqrtf(var) + 1e-9f;
    float inv = alpha_p[0] / denom;
    float bias = bias_p[0];

    if (OUT_BF16) {
        u16x4 o;
        o[0] = f2b(d0 * inv + bias);
        o[1] = f2b(d1 * inv + bias);
        o[2] = f2b(d2 * inv + bias);
        o[3] = f2b(d3 * inv + bias);
        *(u16x4*)&((unsigned short*)out_v)[(size_t)row * 1024 + t * 4] = o;
    } else {
        f32x4 o;
        o[0] = d0 * inv + bias;
        o[1] = d1 * inv + bias;
        o[2] = d2 * inv + bias;
        o[3] = d3 * inv + bias;
        *(f32x4*)&((float*)out_v)[(size_t)row * 1024 + t * 4] = o;
    }
}

// ---------------- f32 -> bf16 transpose ----------------
__global__ __launch_bounds__(256) void transpose_cast_kernel(const float* __restrict__ in,
                                                             unsigned short* __restrict__ out,
                                                             int R, int C) {
    __shared__ unsigned short tile[32][33];
    const int c0 = blockIdx.x * 32, r0 = blockIdx.y * 32;
    const int x = threadIdx.x, y0 = threadIdx.y;
#pragma unroll
    for (int yy = y0; yy < 32; yy += 8) tile[yy][x] = f2b(in[(size_t)(r0 + yy) * C + c0 + x]);
    __syncthreads();
#pragma unroll
    for (int yy = y0; yy < 32; yy += 8) out[(size_t)(c0 + yy) * R + r0 + x] = tile[x][yy];
}

// ---------------- bf16 [b][s][d] -> [b][d][s] transpose ----------------
__global__ __launch_bounds__(256) void transpose_bf16_batch(const unsigned short* __restrict__ in,
                                                            unsigned short* __restrict__ out) {
    __shared__ unsigned short tile[32][33];
    const int b = blockIdx.z;
    const int d0 = blockIdx.x * 32, s0 = blockIdx.y * 32;
    const unsigned short* I = in + (size_t)b * 1024 * 1024;
    unsigned short* O = out + (size_t)b * 1024 * 1024;
    const int x = threadIdx.x, y0 = threadIdx.y;
#pragma unroll
    for (int yy = y0; yy < 32; yy += 8) tile[yy][x] = I[(size_t)(s0 + yy) * 1024 + d0 + x];
    __syncthreads();
#pragma unroll
    for (int yy = y0; yy < 32; yy += 8) O[(size_t)(d0 + yy) * 1024 + s0 + x] = tile[x][yy];
}

// ---------------- GEMM v2: global_load_lds staging, BK=64, both-sides XOR swizzle ----------------
// C[M,N] = A[M,K](bf16) @ Bt[N,K]^T(bf16) + bias(f32) (+res f32). 4 waves 2x2.
// LDS layout: [row][64] bf16 linear (gl_lds needs contiguous dest); global SOURCE chunk
// pre-swizzled ch^=(row&7); ds_read applies the same XOR (involution) -> conflict-free.
template <int BM, int BN, bool RELU, bool RES, bool OUT_BF16>
__global__ __launch_bounds__(256) void gemm2(const unsigned short* __restrict__ A,
                                             const unsigned short* __restrict__ Bt,
                                             const float* __restrict__ bias,
                                             const float* __restrict__ res,
                                             void* __restrict__ C_v,
                                             int M, int N, int K) {
    constexpr int WM = BM / 2, WN = BN / 2;
    constexpr int FM = WM / 16, FN = WN / 16;
    __shared__ __align__(16) unsigned short As[BM * 64];
    __shared__ __align__(16) unsigned short Bs[BN * 64];

    const int t = threadIdx.x;
    const int lane = t & 63, w = t >> 6;
    const int wr = w >> 1, wc = w & 1;
    const int lr = lane & 15, g = lane >> 4;

    // XCD-aware swizzle over 1D grid (nwg % 8 == 0 for all our shapes)
    const int nwg = gridDim.x;
    const int cpx = nwg >> 3;
    const int wg = blockIdx.x;
    const int swz = (wg & 7) * cpx + (wg >> 3);
    const int NB = N / BN;
    const int m0 = (swz / NB) * BM, n0 = (swz % NB) * BN;

    f32x4 acc[FM][FN];
#pragma unroll
    for (int i = 0; i < FM; ++i)
#pragma unroll
        for (int j = 0; j < FN; ++j) acc[i][j] = (f32x4)0.0f;

    for (int k0 = 0; k0 < K; k0 += 64) {
        __syncthreads();  // prev-iter LDS reads done before overwrite
#pragma unroll
        for (int i = 0; i < BM / 32; ++i) {
            int id = i * 256 + t;
            int row = id >> 3, ch = id & 7;
            gld_lds16(&A[(size_t)(m0 + row) * K + k0 + ((ch ^ (row & 7)) * 8)],
                      &As[(size_t)(i * 256 + (t & ~63)) * 8]);
        }
#pragma unroll
        for (int i = 0; i < BN / 32; ++i) {
            int id = i * 256 + t;
            int row = id >> 3, ch = id & 7;
            gld_lds16(&Bt[(size_t)(n0 + row) * K + k0 + ((ch ^ (row & 7)) * 8)],
                      &Bs[(size_t)(i * 256 + (t & ~63)) * 8]);
        }
        __syncthreads();  // drains vmcnt(0) then barrier -> staged data visible

        short8 af[FM][2], bfr[FN][2];
#pragma unroll
        for (int mi = 0; mi < FM; ++mi) {
            int row = wr * WM + mi * 16 + lr;
#pragma unroll
            for (int ks = 0; ks < 2; ++ks) {
                int ch = (ks * 4 + g) ^ (row & 7);
                af[mi][ks] = *(const short8*)&As[row * 64 + ch * 8];
            }
        }
#pragma unroll
        for (int ni = 0; ni < FN; ++ni) {
            int row = wc * WN + ni * 16 + lr;
#pragma unroll
            for (int ks = 0; ks < 2; ++ks) {
                int ch = (ks * 4 + g) ^ (row & 7);
                bfr[ni][ks] = *(const short8*)&Bs[row * 64 + ch * 8];
            }
        }
#pragma unroll
        for (int ks = 0; ks < 2; ++ks)
#pragma unroll
            for (int mi = 0; mi < FM; ++mi)
#pragma unroll
                for (int ni = 0; ni < FN; ++ni)
                    acc[mi][ni] = __builtin_amdgcn_mfma_f32_16x16x32_bf16(af[mi][ks], bfr[ni][ks], acc[mi][ni], 0, 0, 0);
    }

    const int lg = g;
#pragma unroll
    for (int ni = 0; ni < FN; ++ni) {
        int col = n0 + wc * WN + ni * 16 + lr;
        float bv = bias[col];
#pragma unroll
        for (int mi = 0; mi < FM; ++mi) {
            int row0 = m0 + wr * WM + mi * 16 + lg * 4;
#pragma unroll
            for (int i = 0; i < 4; ++i) {
                int row = row0 + i;
                float x = acc[mi][ni][i] + bv;
                if (RES) x += res[(size_t)row * N + col];
                if (RELU) x = fmaxf(x, 0.0f);
                if (OUT_BF16)
                    ((unsigned short*)C_v)[(size_t)row * N + col] = f2b(x);
                else
                    ((float*)C_v)[(size_t)row * N + col] = x;
            }
        }
    }
}

// ---------------- MFMA flash attention (unchanged from r3) ----------------
__global__ __launch_bounds__(256) void attn_mfma_kernel(const unsigned short* __restrict__ p,
                                                        const unsigned short* __restrict__ pT,
                                                        unsigned short* __restrict__ out) {
    __shared__ __align__(16) unsigned short Ks[64 * 64];
    __shared__ __align__(16) unsigned short Vt[64 * 64];
    __shared__ __align__(16) unsigned short Ps[4 * 16 * 64];

    const int t = threadIdx.x;
    const int lane = t & 63, w = t >> 6;
    const int lr = lane & 15, g = lane >> 4;
    const int qblk = blockIdx.x;
    const int bh = blockIdx.y;
    const int b = bh >> 4, h = bh & 15;

    const unsigned short* Pm = p + (size_t)b * (1024 * 1024) + h * 64;
    const unsigned short* PT = pT + (size_t)b * (1024 * 1024) + (size_t)(h * 64) * 1024;

    const int q0 = qblk * 64 + w * 16;
    short8 qa0 = *(const short8*)&Pm[(size_t)(q0 + lr) * 1024 + g * 8];
    short8 qa1 = *(const short8*)&Pm[(size_t)(q0 + lr) * 1024 + 32 + g * 8];

    f32x4 acc[4];
#pragma unroll
    for (int i = 0; i < 4; ++i) acc[i] = (f32x4)0.0f;
    float mrow[4] = {-1e30f, -1e30f, -1e30f, -1e30f};
    float lsum[4] = {0.f, 0.f, 0.f, 0.f};

    unsigned short* Pw = &Ps[w * 16 * 64];

    for (int kt = 0; kt < 16; ++kt) {
        const int key0 = kt * 64;
        __syncthreads();
#pragma unroll
        for (int i = 0; i < 2; ++i) {
            int id = t + i * 256;
            int row = id >> 3, ch = (id & 7) * 8;
            int sw = ch ^ ((row & 7) << 3);
            short8 kv = *(const short8*)&Pm[(size_t)(key0 + row) * 1024 + ch];
            *(short8*)&Ks[row * 64 + sw] = kv;
            short8 vv = *(const short8*)&PT[(size_t)row * 1024 + key0 + ch];
            *(short8*)&Vt[row * 64 + sw] = vv;
        }
        __syncthreads();

        f32x4 s_acc[4];
#pragma unroll
        for (int kg = 0; kg < 4; ++kg) {
            s_acc[kg] = (f32x4)0.0f;
            int krow = kg * 16 + lr;
            int swz = (krow & 7) << 3;
            short8 kb0 = *(const short8*)&Ks[krow * 64 + ((g * 8) ^ swz)];
            short8 kb1 = *(const short8*)&Ks[krow * 64 + ((32 + g * 8) ^ swz)];
            s_acc[kg] = __builtin_amdgcn_mfma_f32_16x16x32_bf16(qa0, kb0, s_acc[kg], 0, 0, 0);
            s_acc[kg] = __builtin_amdgcn_mfma_f32_16x16x32_bf16(qa1, kb1, s_acc[kg], 0, 0, 0);
        }

#pragma unroll
        for (int reg = 0; reg < 4; ++reg) {
            float mx = fmaxf(fmaxf(s_acc[0][reg], s_acc[1][reg]),
                             fmaxf(s_acc[2][reg], s_acc[3][reg])) * 0.125f;
            mx = fmaxf(mx, __shfl_xor(mx, 1));
            mx = fmaxf(mx, __shfl_xor(mx, 2));
            mx = fmaxf(mx, __shfl_xor(mx, 4));
            mx = fmaxf(mx, __shfl_xor(mx, 8));
            float mnew = fmaxf(mrow[reg], mx);
            float scale = __expf(mrow[reg] - mnew);
            mrow[reg] = mnew;
            float psum = 0.f;
#pragma unroll
            for (int kg = 0; kg < 4; ++kg) {
                float pv = __expf(s_acc[kg][reg] * 0.125f - mnew);
                s_acc[kg][reg] = pv;
                psum += pv;
            }
            psum += __shfl_xor(psum, 1);
            psum += __shfl_xor(psum, 2);
            psum += __shfl_xor(psum, 4);
            psum += __shfl_xor(psum, 8);
            lsum[reg] = lsum[reg] * scale + psum;
#pragma unroll
            for (int dg = 0; dg < 4; ++dg) acc[dg][reg] *= scale;
        }

#pragma unroll
        for (int reg = 0; reg < 4; ++reg) {
            int q = g * 4 + reg;
            int swz = (q & 7) << 3;
#pragma unroll
            for (int kg = 0; kg < 4; ++kg) {
                int key = lr + 16 * kg;
                Pw[q * 64 + (key ^ swz)] = f2b(s_acc[kg][reg]);
            }
        }
        int pswz = (lr & 7) << 3;
        short8 pa0 = *(const short8*)&Pw[lr * 64 + ((g * 8) ^ pswz)];
        short8 pa1 = *(const short8*)&Pw[lr * 64 + ((32 + g * 8) ^ pswz)];

#pragma unroll
        for (int dg = 0; dg < 4; ++dg) {
            int drow = dg * 16 + lr;
            int swz = (drow & 7) << 3;
            short8 vb0 = *(const short8*)&Vt[drow * 64 + ((g * 8) ^ swz)];
            short8 vb1 = *(const short8*)&Vt[drow * 64 + ((32 + g * 8) ^ swz)];
            acc[dg] = __builtin_amdgcn_mfma_f32_16x16x32_bf16(pa0, vb0, acc[dg], 0, 0, 0);
            acc[dg] = __builtin_amdgcn_mfma_f32_16x16x32_bf16(pa1, vb1, acc[dg], 0, 0, 0);
        }
    }

    unsigned short* O = out + (size_t)b * (1024 * 1024) + h * 64;
#pragma unroll
    for (int reg = 0; reg < 4; ++reg) {
        float inv = 1.0f / lsum[reg];
        int q = q0 + g * 4 + reg;
#pragma unroll
        for (int dg = 0; dg < 4; ++dg) {
            O[(size_t)q * 1024 + dg * 16 + lr] = f2b(acc[dg][reg] * inv);
        }
    }
}

// ---------------- launch ----------------
extern "C" void kernel_launch(void* const* d_in, const int* in_sizes, int n_in,
                              void* d_out, int out_size, void* d_ws, size_t ws_size,
                              hipStream_t stream) {
    const float* x = (const float*)d_in[0];
    const float* wq_w = (const float*)d_in[1];
    const float* wq_b = (const float*)d_in[2];
    const float* wo_w = (const float*)d_in[3];
    const float* wo_b = (const float*)d_in[4];
    const float* ff1_w = (const float*)d_in[5];
    const float* ff1_b = (const float*)d_in[6];
    const float* ff2_w = (const float*)d_in[7];
    const float* ff2_b = (const float*)d_in[8];
    const float* alpha1 = (const float*)d_in[9];
    const float* bias1 = (const float*)d_in[10];
    const float* alpha2 = (const float*)d_in[11];
    const float* bias2 = (const float*)d_in[12];
    const float* alpha3 = (const float*)d_in[13];
    const float* bias3 = (const float*)d_in[14];
    float* out = (float*)d_out;

    const size_t MB = 1u << 20;
    char* ws = (char*)d_ws;
    unsigned short* wq_t = (unsigned short*)(ws + 0 * MB);
    unsigned short* wo_t = (unsigned short*)(ws + 2 * MB);
    unsigned short* ff1_t = (unsigned short*)(ws + 4 * MB);
    unsigned short* ff2_t = (unsigned short*)(ws + 12 * MB);
    unsigned short* lnbuf = (unsigned short*)(ws + 20 * MB);
    unsigned short* pbuf = (unsigned short*)(ws + 28 * MB);
    unsigned short* attn = (unsigned short*)(ws + 36 * MB);
    float* h1 = (float*)(ws + 44 * MB);
    unsigned short* pbT = (unsigned short*)(ws + 60 * MB);
    unsigned short* mid = (unsigned short*)(ws + 60 * MB);
    float* h2 = (float*)(ws + 28 * MB);

    const int M = 4096;

    transpose_cast_kernel<<<dim3(32, 32), dim3(32, 8), 0, stream>>>(wq_w, wq_t, 1024, 1024);
    transpose_cast_kernel<<<dim3(32, 32), dim3(32, 8), 0, stream>>>(wo_w, wo_t, 1024, 1024);
    transpose_cast_kernel<<<dim3(128, 32), dim3(32, 8), 0, stream>>>(ff1_w, ff1_t, 1024, 4096);
    transpose_cast_kernel<<<dim3(32, 128), dim3(32, 8), 0, stream>>>(ff2_w, ff2_t, 4096, 1024);

    ln_kernel<true><<<M, 256, 0, stream>>>(x, lnbuf, alpha1, bias1);
    // p = ln1 @ wq + wq_b   (M=4096,N=1024,K=1024) -> 512 blocks
    gemm2<128, 64, false, false, true><<<512, 256, 0, stream>>>(lnbuf, wq_t, wq_b, nullptr, pbuf, M, 1024, 1024);
    transpose_bf16_batch<<<dim3(32, 32, 4), dim3(32, 8), 0, stream>>>(pbuf, pbT);
    attn_mfma_kernel<<<dim3(16, 64), 256, 0, stream>>>(pbuf, pbT, attn);
    // h1 = x + attn @ wo + wo_b
    gemm2<128, 64, false, true, false><<<512, 256, 0, stream>>>(attn, wo_t, wo_b, x, h1, M, 1024, 1024);
    ln_kernel<true><<<M, 256, 0, stream>>>(h1, lnbuf, alpha2, bias2);
    // mid = relu(ln2 @ ff1 + ff1_b)  (N=4096) -> 1024 blocks
    gemm2<128, 128, true, false, true><<<1024, 256, 0, stream>>>(lnbuf, ff1_t, ff1_b, nullptr, mid, M, 4096, 1024);
    // h2 = h1 + mid @ ff2 + ff2_b   (K=4096)
    gemm2<128, 64, false, true, false><<<512, 256, 0, stream>>>(mid, ff2_t, ff2_b, h1, h2, M, 1024, 4096);
    ln_kernel<false><<<M, 256, 0, stream>>>(h2, out, alpha3, bias3);
}